// Round 14
// baseline (473.018 us; speedup 1.0000x reference)
//
#include <hip/hip_runtime.h>
#include <hip/hip_bf16.h>

#define SQRT2C 1.41421356237309515f
#define LEAKF 0.2f

typedef __attribute__((ext_vector_type(4))) float f32x4;
typedef __attribute__((ext_vector_type(8))) __bf16 bf16x8;
typedef unsigned int u32x4 __attribute__((ext_vector_type(4)));

#define GLOAD16(g, l) \
  __builtin_amdgcn_global_load_lds((const __attribute__((address_space(1))) void*)(const void*)(g), \
                                   (__attribute__((address_space(3))) void*)(void*)(l), 16, 0, 0)

__device__ __forceinline__ unsigned short f2bf(float f) {
  unsigned int u = __float_as_uint(f);
  unsigned int r = (u + 0x7fffu + ((u >> 16) & 1u)) >> 16;
  return (unsigned short)r;
}
__device__ __forceinline__ float bflo(unsigned int w) { return __uint_as_float(w << 16); }
__device__ __forceinline__ float bfhi(unsigned int w) { return __uint_as_float(w & 0xffff0000u); }

// blur 1-D factor: B1 = [1,3,3,1], zero outside.  Ty[rp][u][k] == B1v(4-2u-k+rp)  (verified r1-r13)
constexpr float B1v(int c) { return (c < 0 || c > 3) ? 0.f : ((c == 0 || c == 3) ? 1.f : 3.f); }

// ---------------- s = w @ aff_w.T + aff_b + 1 ----------------
__global__ void k_affine(const float* __restrict__ w, const float* __restrict__ aw,
                         const float* __restrict__ ab, float* __restrict__ s, int C) {
  int wid = (blockIdx.x * blockDim.x + threadIdx.x) >> 6;
  int lane = threadIdx.x & 63;
  int b = wid / C, i = wid % C;
  const float* wr = w + (size_t)b * 512;
  const float* ar = aw + (size_t)i * 512;
  float acc = 0.f;
  #pragma unroll
  for (int l = 0; l < 512; l += 64) acc += wr[l + lane] * ar[l + lane];
  #pragma unroll
  for (int off = 32; off; off >>= 1) acc += __shfl_down(acc, off, 64);
  if (lane == 0) s[wid] = acc + ab[i] + 1.0f;
}

// ---------------- d[b,o] = rsqrt(sum_i s^2 * sum_tap w^2 + 1e-8) ----------------
__global__ void k_demod(const float* __restrict__ weight, const float* __restrict__ s,
                        float* __restrict__ d, int CIN) {
  int o = blockIdx.x & 255, b = blockIdx.x >> 8;
  int t = threadIdx.x;
  const float* wr = weight + (size_t)o * CIN * 9;
  const float* sr = s + (size_t)b * CIN;
  float acc = 0.f;
  for (int i = t; i < CIN; i += 256) {
    float sv = sr[i];
    float ws = 0.f;
    #pragma unroll
    for (int k = 0; k < 9; ++k) { float w = wr[(size_t)i * 9 + k]; ws += w * w; }
    acc += sv * sv * ws;
  }
  __shared__ float red[256];
  red[t] = acc; __syncthreads();
  for (int h = 128; h; h >>= 1) { if (t < h) red[t] += red[t + h]; __syncthreads(); }
  if (t == 0) d[blockIdx.x] = rsqrtf(red[0] + 1e-8f);
}

// ---- Am2[bb][kk=ky*3+kx][o][i] = modulated wm1 (bf16) for batch slice {b0, b0+1} ----
__global__ void k_wmod(const float* __restrict__ w1, const float* __restrict__ s1,
                       const float* __restrict__ d1, unsigned short* __restrict__ Am, int b0) {
  int t = blockIdx.x * 256 + threadIdx.x;   // 2*256*512 threads
  int i = t & 511, o = (t >> 9) & 255, bb = t >> 17;
  int b = b0 + bb;
  float sd = s1[b * 512 + i] * d1[b * 256 + o];
  const float* wp = w1 + ((size_t)o * 512 + i) * 9;
  #pragma unroll
  for (int k = 0; k < 9; ++k)
    Am[((size_t)(bb * 9 + k) * 256 + o) * 512 + i] = f2bf(wp[k] * sd);
}

// ---------------- W2m[b][tap][o][i] (bf16) ----------------
__global__ void k_weff2(const float* __restrict__ w2, const float* __restrict__ s2,
                        const float* __restrict__ d2, unsigned short* __restrict__ Wm) {
  int t = blockIdx.x * 256 + threadIdx.x;   // 8*256*256 threads
  int i = t & 255, o = (t >> 8) & 255, b = t >> 16;
  float sd = s2[b * 256 + i] * d2[b * 256 + o];
  const float* wp = w2 + ((size_t)o * 256 + i) * 9;
  #pragma unroll
  for (int k = 0; k < 9; ++k)
    Wm[((size_t)(b * 9 + k) * 256 + o) * 256 + i] = f2bf(wp[k] * sd);
}

// ---------------- border-only zero fill for y1p halo ----------------
__global__ void k_border_y1(unsigned short* __restrict__ y1p) {
  int t = blockIdx.x * 256 + threadIdx.x;   // 8*516*32 threads, 1 uint4 each
  int l = t & 31;
  int c = (t >> 5) % 516;
  int b = (t >> 5) / 516;
  int p_, q_;
  if (c < 130)      { p_ = 0;       q_ = c; }
  else if (c < 260) { p_ = 129;     q_ = c - 130; }
  else if (c < 388) { p_ = c - 259; q_ = 0; }
  else              { p_ = c - 387; q_ = 129; }
  uint4* p = (uint4*)(y1p + (((size_t)(b * 130) + p_) * 130 + q_) * 256);
  p[l] = make_uint4(0u, 0u, 0u, 0u);
}

// ---- x [8][512][64][64] f32 -> xt [8][4096][512] bf16 (pixel-linear, NO halo: 1x1 GEMM) ----
__global__ void k_txpose(const float* __restrict__ x, unsigned short* __restrict__ xt) {
  int bid = blockIdx.x;            // 8192 = b(8) * y(64) * x0(2) * i0(8)
  int i0 = (bid & 7) * 64;
  int x0 = ((bid >> 3) & 1) * 32;
  int y  = (bid >> 4) & 63;
  int b  = bid >> 10;
  int tx = threadIdx.x & 31, ty = threadIdx.x >> 5;
  __shared__ float tile[64][33];
  const float* xp = x + ((size_t)(b * 512 + i0) * 64 + y) * 64 + x0;
  for (int ii = ty; ii < 64; ii += 8) tile[ii][tx] = xp[(size_t)ii * 4096 + tx];
  __syncthreads();
  unsigned short* op = xt + ((size_t)(b * 4096) + y * 64 + x0) * 512 + i0;
  for (int xx = ty; xx < 32; xx += 8) {
    int iL = tx * 2;
    unsigned int pk = (unsigned int)f2bf(tile[iL][xx]) | ((unsigned int)f2bf(tile[iL + 1][xx]) << 16);
    *(unsigned int*)&op[(size_t)xx * 512 + iL] = pk;
  }
}

// ================= 256x256 tile, 8-wave, BK=64, 2-buffer, 8-PHASE GEMM =========
// OM=0: 1x1 Z-GEMM over batch pair (RHO_N=9 tap panels, TAPS=1); Z[bb][rho][pix][o] bf16.
// OM=2: conv2 3x3 on halo grid, f32 output with noise/bias/lrelu.
template<int CIN, int GSH, int HP, int RHO_N, int TAPS, int PANB, int OM>
__global__ __launch_bounds__(512, 2) void k_gemm8p(
    const unsigned short* __restrict__ Xt,
    const unsigned short* __restrict__ Wt,
    const float* __restrict__ noise,
    const float* __restrict__ nsp,
    const float* __restrict__ bias,
    unsigned short* __restrict__ Yb,
    float* __restrict__ Yf)
{
  constexpr int GRID = 1 << GSH;
  constexpr int NT = (GRID * GRID) / 256;
  constexpr int NKT = TAPS * (CIN / 64);   // K-tiles of 64
  constexpr int NIT = NKT / 2;             // 2 K-tiles per iteration
  constexpr int KSH = (CIN == 512) ? 3 : 2;
  constexpr int KMASK = (CIN / 64) - 1;
  constexpr int TOT = NT * RHO_N * ((OM == 0) ? 2 : 8);
  extern __shared__ char smem[];

  int bid0 = blockIdx.x;
  int bid = (bid0 & 7) * (TOT / 8) + (bid0 >> 3);   // XCD-chunked, bijective (TOT%8==0)
  int nt = bid % NT;
  int rho = (bid / NT) % RHO_N;
  int b = bid / (NT * RHO_N);
  int pix0 = nt * 256;
  int tid = threadIdx.x, lane = tid & 63, w = tid >> 6;
  int lr = lane & 15, lq = lane >> 4;
  int wr = w >> 2, wc = w & 3;
  int lhi = lane >> 3, llo = lane & 7;
  int ksrc = ((llo ^ lhi) << 3);            // inverse-swizzled per-lane k element offset

  const unsigned short* Wp = Wt + ((size_t)b * PANB + rho * TAPS) * 256 * CIN;
  size_t aOff = (size_t)(w * 8 + lhi) * CIN + ksrc;
  size_t bOff = (size_t)lhi * CIN + ksrc;
  const unsigned short* XtB;
  if constexpr (OM != 2) XtB = Xt + (size_t)b * GRID * 64 * CIN;               // pixel-linear
  else                   XtB = Xt + ((size_t)(b * HP + (pix0 >> 7))) * 130 * CIN;

  // ---- staging: one unit = 128 rows x 128 B = 16 KB = 2 gload_lds/thread ----
  auto stageA = [&](int buf, int t, int u) {
    int tap = t >> KSH; size_t ke = (size_t)((t & KMASK) << 6);
    const unsigned short* s = Wp + (size_t)tap * 256 * CIN + ke + (size_t)u * 64 * CIN + aOff;
    char* d = smem + buf * 65536 + u * 8192 + w * 1024;
    GLOAD16(s, d);
    GLOAD16(s + (size_t)128 * CIN, d + 16384);
  };
  auto stageB = [&](int buf, int t, int u) {
    int tap = t >> KSH; size_t ke = (size_t)((t & KMASK) << 6);
    size_t tk;
    if constexpr (OM != 2) tk = (size_t)tap * 64 * CIN + ke;
    else                   tk = ((size_t)(tap / 3) * HP + (tap % 3)) * CIN + ke;
    int c0 = w >> 2, r0 = (w & 3) * 8;
    int rowA = c0 * 64 + u * 32 + r0;
    int rowB = rowA + 128;
    char* db = smem + buf * 65536 + 32768;
    size_t sA, sB;
    if constexpr (OM != 2) { sA = (size_t)(pix0 + rowA) * CIN; sB = (size_t)(pix0 + rowB) * CIN; }
    else { sA = ((size_t)(rowA >> 7) * 130 + (rowA & 127)) * CIN;
           sB = ((size_t)(rowB >> 7) * 130 + (rowB & 127)) * CIN; }
    GLOAD16(XtB + sA + tk + bOff, db + rowA * 128);
    GLOAD16(XtB + sB + tk + bOff, db + rowB * 128);
  };

  // ---- fragment reads (swizzled) ----
  int ldsA = (wr * 128 + lr) * 128;
  int ldsB = 32768 + (wc * 64 + lr) * 128;
  int xk[2] = { (lq * 16) ^ ((lr & 7) << 4), (64 + lq * 16) ^ ((lr & 7) << 4) };

  f32x4 acc[8][4];
  #pragma unroll
  for (int m = 0; m < 8; ++m)
    #pragma unroll
    for (int n = 0; n < 4; ++n) acc[m][n] = (f32x4){0.f, 0.f, 0.f, 0.f};

  bf16x8 af[2][4], bv[2][4];
  auto readA = [&](const char* base, int mq) {
    #pragma unroll
    for (int kk = 0; kk < 2; ++kk)
      #pragma unroll
      for (int m = 0; m < 4; ++m)
        af[kk][m] = *(const bf16x8*)(base + ldsA + (mq * 4 + m) * 2048 + xk[kk]);
  };
  auto readB = [&](const char* base, int nq) {
    #pragma unroll
    for (int kk = 0; kk < 2; ++kk)
      #pragma unroll
      for (int n = 0; n < 2; ++n)
        bv[kk][nq * 2 + n] = *(const bf16x8*)(base + ldsB + (nq * 2 + n) * 2048 + xk[kk]);
  };
  auto mma = [&](int mq, int nq) {
    __builtin_amdgcn_s_setprio(1);
    #pragma unroll
    for (int kk = 0; kk < 2; ++kk)
      #pragma unroll
      for (int m = 0; m < 4; ++m)
        #pragma unroll
        for (int n = 0; n < 2; ++n)
          acc[mq * 4 + m][nq * 2 + n] = __builtin_amdgcn_mfma_f32_16x16x32_bf16(
              af[kk][m], bv[kk][nq * 2 + n], acc[mq * 4 + m][nq * 2 + n], 0, 0, 0);
    __builtin_amdgcn_s_setprio(0);
  };

#define PH_SYNC()  __builtin_amdgcn_s_barrier(); \
                   asm volatile("s_waitcnt lgkmcnt(0)" ::: "memory")
#define PH_END()   __builtin_amdgcn_s_barrier()

  stageA(0, 0, 0); stageB(0, 0, 0); stageA(0, 0, 1); stageB(0, 0, 1);
  stageA(1, 1, 0); stageB(1, 1, 0);
  asm volatile("s_waitcnt vmcnt(4)" ::: "memory");
  __builtin_amdgcn_s_barrier();

  const char* B0 = smem;
  const char* B1 = smem + 65536;

  #pragma unroll 1
  for (int i = 0; i < NIT; ++i) {
    int a = 2 * i;
    bool nl = (i + 1 < NIT);
    readA(B0, 0); readB(B0, 0);
    stageA(1, a + 1, 1);
    PH_SYNC(); mma(0, 0); PH_END();
    readB(B0, 1);
    stageB(1, a + 1, 1);
    PH_SYNC(); mma(0, 1); PH_END();
    readA(B0, 1);
    if (nl) stageA(0, a + 2, 0);
    PH_SYNC(); mma(1, 0); PH_END();
    if (nl) stageB(0, a + 2, 0);
    PH_SYNC(); mma(1, 1);
    if (nl) { asm volatile("s_waitcnt vmcnt(4)" ::: "memory"); }
    else    { asm volatile("s_waitcnt vmcnt(0)" ::: "memory"); }
    PH_END();
    readA(B1, 0); readB(B1, 0);
    if (nl) stageA(0, a + 2, 1);
    PH_SYNC(); mma(0, 0); PH_END();
    readB(B1, 1);
    if (nl) stageB(0, a + 2, 1);
    PH_SYNC(); mma(0, 1); PH_END();
    readA(B1, 1);
    if (nl) stageA(1, a + 3, 0);
    PH_SYNC(); mma(1, 0); PH_END();
    if (nl) stageB(1, a + 3, 0);
    PH_SYNC(); mma(1, 1);
    if (nl) { asm volatile("s_waitcnt vmcnt(4)" ::: "memory"); }
    PH_END();
  }
#undef PH_SYNC
#undef PH_END

  // ---- epilogue ----
  if constexpr (OM == 2) {
    float ns = nsp[0];
    #pragma unroll
    for (int m = 0; m < 8; ++m) {
      int o = wr * 128 + m * 16 + lq * 4;
      #pragma unroll
      for (int n = 0; n < 4; ++n) {
        int pix = pix0 + wc * 64 + n * 16 + lr;
        int p = pix >> 7, q = pix & 127;
        float nz = ns * noise[((size_t)b << 14) + (p << 7) + q];
        #pragma unroll
        for (int r = 0; r < 4; ++r) {
          float v = acc[m][n][r] + nz + bias[o + r];
          v = (v >= 0.f ? v : LEAKF * v) * SQRT2C;
          __builtin_nontemporal_store(v, &Yf[(((size_t)b * 256 + o + r) << 14) + (p << 7) + q]);
        }
      }
    }
  } else {
    // OM==0: Z[bb][rho][pix][o] bf16
    #pragma unroll
    for (int m = 0; m < 8; ++m) {
      int o = wr * 128 + m * 16 + lq * 4;
      #pragma unroll
      for (int n = 0; n < 4; ++n) {
        int pix = pix0 + wc * 64 + n * 16 + lr;
        ushort4 pk;
        #pragma unroll
        for (int r = 0; r < 4; ++r) ((unsigned short*)&pk)[r] = f2bf(acc[m][n][r]);
        *(ushort4*)&Yb[((size_t)(b * 9 + rho) * 4096 + pix) * 256 + o] = pk;
      }
    }
  }
}

// ---- vertical mix: At[bb][kx][p][gx][o] = sum_{u,ky} Ty[p&1][u][ky] * Z[bb][ky*3+kx][(gy+u-1)*64+gx][o]
__global__ void k_vmix(const unsigned short* __restrict__ Z, unsigned short* __restrict__ At) {
  int bid = blockIdx.x;                  // 6144 = bb(2)*kx(3)*p(128)*gxg(8)
  int gxg = bid & 7;
  int p = (bid >> 3) & 127;
  int rest = bid >> 10;
  int kx = rest % 3, bb = rest / 3;
  int o0 = (threadIdx.x & 31) * 8;
  int gx = gxg * 8 + (threadIdx.x >> 5);
  int gy = p >> 1;
  float rpf = (float)(p & 1);
  float acc[8];
  #pragma unroll
  for (int r = 0; r < 8; ++r) acc[r] = 0.f;
  #pragma unroll
  for (int u = 0; u < 3; ++u) {
    int gyy = gy + u - 1;
    float bmask = (gyy >= 0 && gyy <= 63) ? 1.f : 0.f;
    int gyc = gyy < 0 ? 0 : (gyy > 63 ? 63 : gyy);
    #pragma unroll
    for (int ky = 0; ky < 3; ++ky) {
      float C0 = B1v(4 - 2 * u - ky);
      float C1 = B1v(5 - 2 * u - ky);
      if (C0 == 0.f && C1 == 0.f) continue;            // folds at compile time
      float coef = (C0 + (C1 - C0) * rpf) * bmask;
      u32x4 zv = *(const u32x4*)&Z[(((size_t)(bb * 9 + ky * 3 + kx)) * 4096 + gyc * 64 + gx) * 256 + o0];
      acc[0] += coef * bflo(zv[0]); acc[1] += coef * bfhi(zv[0]);
      acc[2] += coef * bflo(zv[1]); acc[3] += coef * bfhi(zv[1]);
      acc[4] += coef * bflo(zv[2]); acc[5] += coef * bfhi(zv[2]);
      acc[6] += coef * bflo(zv[3]); acc[7] += coef * bfhi(zv[3]);
    }
  }
  u32x4 ov;
  ov[0] = (unsigned)f2bf(acc[0]) | ((unsigned)f2bf(acc[1]) << 16);
  ov[1] = (unsigned)f2bf(acc[2]) | ((unsigned)f2bf(acc[3]) << 16);
  ov[2] = (unsigned)f2bf(acc[4]) | ((unsigned)f2bf(acc[5]) << 16);
  ov[3] = (unsigned)f2bf(acc[6]) | ((unsigned)f2bf(acc[7]) << 16);
  *(u32x4*)&At[(((size_t)(bb * 3 + kx) * 128 + p) * 64 + gx) * 256 + o0] = ov;
}

// ---------------- horizontal mix + epilogue: y1p interior for batch slice ----------------
__global__ void k_hmix(const unsigned short* __restrict__ At, const float* __restrict__ noise,
                       const float* __restrict__ nsp, const float* __restrict__ bias,
                       unsigned short* __restrict__ y1p, int b0) {
  int bid = blockIdx.x;                  // 4096 = bb(2)*p(128)*qg(16)
  int qg = bid & 15;
  int p = (bid >> 4) & 127;
  int bb = bid >> 11;
  int b = b0 + bb;
  int o0 = (threadIdx.x & 31) * 8;
  int q = qg * 8 + (threadIdx.x >> 5);
  int gq = q >> 1;
  float rqf = (float)(q & 1);
  float acc[8];
  #pragma unroll
  for (int r = 0; r < 8; ++r) acc[r] = 0.f;
  #pragma unroll
  for (int v = 0; v < 3; ++v) {
    int gxx = gq + v - 1;
    float bmask = (gxx >= 0 && gxx <= 63) ? 1.f : 0.f;
    int gxc = gxx < 0 ? 0 : (gxx > 63 ? 63 : gxx);
    #pragma unroll
    for (int kx = 0; kx < 3; ++kx) {
      float C0 = B1v(4 - 2 * v - kx);
      float C1 = B1v(5 - 2 * v - kx);
      if (C0 == 0.f && C1 == 0.f) continue;
      float coef = (C0 + (C1 - C0) * rqf) * bmask;
      u32x4 av = *(const u32x4*)&At[(((size_t)(bb * 3 + kx) * 128 + p) * 64 + gxc) * 256 + o0];
      acc[0] += coef * bflo(av[0]); acc[1] += coef * bfhi(av[0]);
      acc[2] += coef * bflo(av[1]); acc[3] += coef * bfhi(av[1]);
      acc[4] += coef * bflo(av[2]); acc[5] += coef * bfhi(av[2]);
      acc[6] += coef * bflo(av[3]); acc[7] += coef * bfhi(av[3]);
    }
  }
  float ns = nsp[0];
  float nz = ns * noise[((size_t)b << 14) + (p << 7) + q];
  float4 bl = *(const float4*)&bias[o0];
  float4 bh = *(const float4*)&bias[o0 + 4];
  float bb8[8] = {bl.x, bl.y, bl.z, bl.w, bh.x, bh.y, bh.z, bh.w};
  unsigned short ov[8];
  #pragma unroll
  for (int r = 0; r < 8; ++r) {
    float vv = acc[r] * 0.0625f + nz + bb8[r];
    vv = (vv >= 0.f ? vv : LEAKF * vv) * SQRT2C;
    ov[r] = f2bf(vv);
  }
  uint4 pk;
  pk.x = (unsigned)ov[0] | ((unsigned)ov[1] << 16);
  pk.y = (unsigned)ov[2] | ((unsigned)ov[3] << 16);
  pk.z = (unsigned)ov[4] | ((unsigned)ov[5] << 16);
  pk.w = (unsigned)ov[6] | ((unsigned)ov[7] << 16);
  *(uint4*)&y1p[(((size_t)(b * 130) + p + 1) * 130 + q + 1) * 256 + o0] = pk;
}

extern "C" void kernel_launch(void* const* d_in, const int* in_sizes, int n_in,
                              void* d_out, int out_size, void* d_ws, size_t ws_size,
                              hipStream_t stream) {
  (void)in_sizes; (void)n_in; (void)out_size; (void)ws_size;
  const float* x       = (const float*)d_in[0];
  const float* w1      = (const float*)d_in[1];
  const float* w2      = (const float*)d_in[2];
  const float* noise1  = (const float*)d_in[3];
  const float* noise2  = (const float*)d_in[4];
  const float* weight1 = (const float*)d_in[5];
  const float* aff1w   = (const float*)d_in[6];
  const float* aff1b   = (const float*)d_in[7];
  const float* weight2 = (const float*)d_in[8];
  const float* aff2w   = (const float*)d_in[9];
  const float* aff2b   = (const float*)d_in[10];
  const float* ns1     = (const float*)d_in[11];
  const float* ns2     = (const float*)d_in[12];
  const float* b1      = (const float*)d_in[13];
  const float* b2      = (const float*)d_in[14];

  // Workspace map (proven-safe bound: <= 189,882,368 B).  SIZES DOUBLE-CHECKED (x2 for bf16):
  //   header        0 ..      40,960
  //   xt       40,960 ..  33,595,392   (8*4096*512*2    = 33,554,432)
  //   W2m  33,595,392 ..  43,032,576   (8*9*256*256*2   =  9,437,184)
  //   y1p  43,032,576 .. 112,254,976   (8*130*130*256*2 = 69,222,400)
  //   Am2 112,254,976 .. 116,973,568   (2*9*256*512*2   =  4,718,592)
  //   Z2  116,973,568 .. 154,722,304   (2*9*4096*256*2  = 37,748,736)
  //   At2 154,722,304 .. 179,888,128   (2*3*128*64*256*2= 25,165,824)
  char* ws = (char*)d_ws;
  float* s1 = (float*)(ws + 0);
  float* s2 = (float*)(ws + 16384);
  float* d1 = (float*)(ws + 24576);
  float* d2 = (float*)(ws + 32768);
  unsigned short* xt   = (unsigned short*)(ws + 40960);
  unsigned short* W2m  = (unsigned short*)(ws + 33595392);
  unsigned short* y1p  = (unsigned short*)(ws + 43032576);
  unsigned short* Am2  = (unsigned short*)(ws + 112254976);
  unsigned short* Z2   = (unsigned short*)(ws + 116973568);
  unsigned short* At2  = (unsigned short*)(ws + 154722304);

  (void)hipFuncSetAttribute((const void*)k_gemm8p<512, 6, 64, 9, 1, 9, 0>,
                            hipFuncAttributeMaxDynamicSharedMemorySize, 131072);
  (void)hipFuncSetAttribute((const void*)k_gemm8p<256, 7, 130, 1, 9, 9, 2>,
                            hipFuncAttributeMaxDynamicSharedMemorySize, 131072);

  k_affine<<<1024, 256, 0, stream>>>(w1, aff1w, aff1b, s1, 512);
  k_affine<<<512,  256, 0, stream>>>(w2, aff2w, aff2b, s2, 256);
  k_demod<<<2048, 256, 0, stream>>>(weight1, s1, d1, 512);
  k_demod<<<2048, 256, 0, stream>>>(weight2, s2, d2, 256);
  k_weff2<<<2048, 256, 0, stream>>>(weight2, s2, d2, W2m);
  k_txpose<<<8192, 256, 0, stream>>>(x, xt);
  k_border_y1<<<516, 256, 0, stream>>>(y1p);

  // conv1 path, sliced by batch pairs: Z-GEMM (K=512, 9 tap panels) -> vmix -> hmix
  for (int s = 0; s < 4; ++s) {
    int b0 = s * 2;
    k_wmod<<<1024, 256, 0, stream>>>(weight1, s1, d1, Am2, b0);
    k_gemm8p<512, 6, 64, 9, 1, 9, 0><<<288, 512, 131072, stream>>>(
        xt + (size_t)b0 * 4096 * 512, Am2, nullptr, nullptr, nullptr, Z2, nullptr);
    k_vmix<<<6144, 256, 0, stream>>>(Z2, At2);
    k_hmix<<<4096, 256, 0, stream>>>(At2, noise1, ns1, b1, y1p, b0);
  }

  // conv2: 3x3 on halo grid, K=2304
  k_gemm8p<256, 7, 130, 1, 9, 9, 2><<<512, 512, 131072, stream>>>(
      y1p, W2m, noise2, ns2, b2, nullptr, (float*)d_out);
}